// Round 6
// baseline (713.539 us; speedup 1.0000x reference)
//
#include <hip/hip_runtime.h>
#include <math.h>

#define TSTEPS 288
#define NTHREADS 512

typedef float f32x2 __attribute__((ext_vector_type(2)));

__device__ __forceinline__ float sigmoidf_(float x) {
    return 1.0f / (1.0f + __expf(-x));
}

// Packed 2xf32 FMA: acc.{lo,hi} += w.{lo,hi} * x.{lo,hi}. One VALU slot for
// two FMAs (the only way to the 157 TF fp32 peak). Non-volatile: scheduler
// may reorder; inputs/outputs fully described by constraints.
__device__ __forceinline__ void pkfma(f32x2& acc, f32x2 w, f32x2 x) {
    asm("v_pk_fma_f32 %0, %1, %2, %0" : "+v"(acc) : "v"(w), "v"(x));
}

// Butterfly all-reduce over the low log2(NS) lane bits.
// xor1/xor2 via DPP quad_perm (pure VALU); xor4 via ds_swizzle.
template<int NS>
__device__ __forceinline__ float allreduce_seg(float v) {
    if constexpr (NS > 1)
        v += __int_as_float(__builtin_amdgcn_update_dpp(
                0, __float_as_int(v), 0xB1, 0xF, 0xF, true));   // quad_perm xor 1
    if constexpr (NS > 2)
        v += __int_as_float(__builtin_amdgcn_update_dpp(
                0, __float_as_int(v), 0x4E, 0xF, 0xF, true));   // quad_perm xor 2
    if constexpr (NS > 4)
        v += __int_as_float(__builtin_amdgcn_ds_swizzle(
                __float_as_int(v), 0x101F));                    // xor 4
    return v;
}

// Conflict-free LDS layout: a region read by (NS,KSEG)-readers stores the
// float4 #k4 of segment seg at float offset (k4*NS+seg)*4. A wave's parallel
// reads (fixed k4, seg varying) then hit 4*NS distinct banks instead of
// aliasing at stride KSEG. perm_idx maps logical element j -> float offset.
template<int NS, int KSEG>
__device__ __forceinline__ int perm_idx(int j) {
    return (((j % KSEG) >> 2) * NS + (j / KSEG)) * 4 + (j & 3);
}

// One block = one sample. Thread (u, seg): u = tid>>S owns unit u's 4 gate
// columns; seg = tid&(NS-1) covers KIN input + KH hidden rows. Cross-seg
// reduce = in-wave butterfly; gate update redundant across seg lanes.
// One barrier per timestep, xh ping-pong. SEQNS/SEQK: the NEXT layer's
// (NS,KIN) - used to permute this layer's seq writes for its reader.
template<int DIN, int U, int NS, int ACTIVE, int SEQNS, int SEQK,
         bool FIRST, bool WRITE_NOW, bool WRITE_DELAY>
__device__ void run_layer(const float* __restrict__ Wk,
                          const float* __restrict__ Wr,
                          const float* __restrict__ bias,
                          const float* __restrict__ xg,   // x + b*T*64 (FIRST only)
                          float* __restrict__ seq,
                          float* __restrict__ xh,         // 2 x 128 ping-pong
                          float* __restrict__ xring,      // 2 x 64 input ring
                          int tid)
{
    constexpr int KIN  = DIN / NS;
    constexpr int KH   = U / NS;
    constexpr int COLS = 4 * U;
    constexpr int S    = (NS == 4) ? 2 : 3;
    constexpr int NPI  = KIN / 2;            // input weight pairs
    constexpr int NPH  = KH / 2;             // hidden weight pairs
    static_assert(ACTIVE == NS * U, "thread mapping");
    static_assert(KIN % 4 == 0 && (KH % 4 == 0), "float4 alignment");
    static_assert(NS <= 8, "butterfly width");

    const int seg = tid & (NS - 1);
    const int u   = tid >> S;
    const bool act = tid < ACTIVE;

    f32x2 w[4][NPI + NPH];
    float bz[4] = {0.f, 0.f, 0.f, 0.f};
    float cst = 0.0f, hprev = 0.0f;

    if (act) {
        // ---- register-resident weights, packed in pairs along k ----
#pragma unroll
        for (int p = 0; p < NPI; ++p) {
            const int k0 = seg * KIN + 2 * p;
#pragma unroll
            for (int g = 0; g < 4; ++g) {
                const int c = g * U + u;
                w[g][p] = f32x2{Wk[(size_t)k0 * COLS + c],
                                Wk[(size_t)(k0 + 1) * COLS + c]};
            }
        }
#pragma unroll
        for (int p = 0; p < NPH; ++p) {
            const int k0 = seg * KH + 2 * p;
#pragma unroll
            for (int g = 0; g < 4; ++g) {
                const int c = g * U + u;
                w[g][NPI + p] = f32x2{Wr[(size_t)k0 * COLS + c],
                                      Wr[(size_t)(k0 + 1) * COLS + c]};
            }
        }
        if (seg == 0) {
#pragma unroll
            for (int g = 0; g < 4; ++g) bz[g] = bias[g * U + u];
        }
        // Pin pairs in registers: loaded value becomes asm output ->
        // cannot be rematerialized/sunk into the t-loop.
#pragma unroll
        for (int g = 0; g < 4; ++g)
#pragma unroll
            for (int p = 0; p < NPI + NPH; ++p)
                asm volatile("" : "+v"(w[g][p]));
    }
    if (tid < 128) xh[tid] = 0.0f;                 // zero t=0 read buffer
    if (FIRST && tid < 64)                         // stage x row 0 (permuted)
        xring[perm_idx<4, 16>(tid)] = xg[tid];
    __syncthreads();

    for (int t = 0; t < TSTEPS; ++t) {
        if (act) {
            const float* __restrict__ xr = xh + (t & 1) * 128;
            float* __restrict__ xw       = xh + ((t + 1) & 1) * 128;

            // L1 input staging: 64 threads fetch row t+1 (coalesced 256B).
            float xstage = 0.0f;
            if (FIRST && tid < 64 && (t + 1) < TSTEPS)
                xstage = xg[(t + 1) * 64 + tid];

            f32x2 ac0 = {0.f, 0.f}, ac1 = {0.f, 0.f},
                  ac2 = {0.f, 0.f}, ac3 = {0.f, 0.f};

            // ---- input-projection part (conflict-free strided float4) ----
            {
                const float4* in4 = reinterpret_cast<const float4*>(
                    FIRST ? (xring + (t & 1) * 64) : (seq + t * 128)) + seg;
#pragma unroll
                for (int k4 = 0; k4 < KIN / 4; ++k4) {
                    const float4 v = in4[k4 * NS];
                    const f32x2 lo = {v.x, v.y}, hi = {v.z, v.w};
                    pkfma(ac0, w[0][2*k4+0], lo); pkfma(ac0, w[0][2*k4+1], hi);
                    pkfma(ac1, w[1][2*k4+0], lo); pkfma(ac1, w[1][2*k4+1], hi);
                    pkfma(ac2, w[2][2*k4+0], lo); pkfma(ac2, w[2][2*k4+1], hi);
                    pkfma(ac3, w[3][2*k4+0], lo); pkfma(ac3, w[3][2*k4+1], hi);
                }
            }
            // ---- recurrent part ----
            {
                const float4* h4 = reinterpret_cast<const float4*>(xr) + seg;
#pragma unroll
                for (int k4 = 0; k4 < KH / 4; ++k4) {
                    const float4 v = h4[k4 * NS];
                    const f32x2 lo = {v.x, v.y}, hi = {v.z, v.w};
                    const int pb = NPI + 2 * k4;
                    pkfma(ac0, w[0][pb], lo); pkfma(ac0, w[0][pb+1], hi);
                    pkfma(ac1, w[1][pb], lo); pkfma(ac1, w[1][pb+1], hi);
                    pkfma(ac2, w[2][pb], lo); pkfma(ac2, w[2][pb+1], hi);
                    pkfma(ac3, w[3][pb], lo); pkfma(ac3, w[3][pb+1], hi);
                }
            }

            // ---- horizontal + bias, then in-wave butterfly reduce ----
            float a0 = (ac0[0] + ac0[1]) + bz[0];
            float a1 = (ac1[0] + ac1[1]) + bz[1];
            float a2 = (ac2[0] + ac2[1]) + bz[2];
            float a3 = (ac3[0] + ac3[1]) + bz[3];
            a0 = allreduce_seg<NS>(a0);
            a1 = allreduce_seg<NS>(a1);
            a2 = allreduce_seg<NS>(a2);
            a3 = allreduce_seg<NS>(a3);

            if constexpr (WRITE_DELAY) {
                if (seg == 0 && t > 0)
                    seq[(t - 1) * 128 + perm_idx<SEQNS, SEQK>(u)] = hprev;
            }

            // ---- gate update (redundant across seg lanes) ----
            const float gi = sigmoidf_(a0);
            const float gf = sigmoidf_(a1);
            const float gg = fmaxf(a2, 0.0f);          // cell activation = relu
            const float go = sigmoidf_(a3);
            cst = fmaf(gf, cst, gi * gg);
            const float h = go * fmaxf(cst, 0.0f);     // output activation = relu

            if (seg == 0) {
                xw[perm_idx<NS, KH>(u)] = h;
                if constexpr (WRITE_NOW)
                    seq[t * 128 + perm_idx<SEQNS, SEQK>(u)] = h;
            }
            hprev = h;

            if (FIRST && tid < 64 && (t + 1) < TSTEPS)
                xring[((t + 1) & 1) * 64 + perm_idx<4, 16>(tid)] = xstage;
        }
        __syncthreads();
    }

    if constexpr (WRITE_DELAY) {
        if (act && seg == 0)
            seq[(TSTEPS - 1) * 128 + perm_idx<SEQNS, SEQK>(u)] = hprev;
    }
}

extern "C" __global__ void __launch_bounds__(NTHREADS, 2)
lstm_stack_kernel(const float* __restrict__ x,
                  const float* __restrict__ W1, const float* __restrict__ U1, const float* __restrict__ b1,
                  const float* __restrict__ W2, const float* __restrict__ U2, const float* __restrict__ b2,
                  const float* __restrict__ W3, const float* __restrict__ U3, const float* __restrict__ b3,
                  const float* __restrict__ W4, const float* __restrict__ U4, const float* __restrict__ b4,
                  const float* __restrict__ Wf, const float* __restrict__ bf,
                  const float* __restrict__ Wo, const float* __restrict__ bo,
                  float* __restrict__ out)
{
    __shared__ __align__(16) float seq[TSTEPS * 128];   // 147456 B
    __shared__ __align__(16) float xh[256 + 16];        // ping-pong h + head tmp
    __shared__ __align__(16) float xring[2 * 64];       // L1 input ring

    const int tid = threadIdx.x;
    const float* xg = x + (size_t)blockIdx.x * TSTEPS * 64;

    //            DIN    U NS ACTIVE SEQNS SEQK  FIRST  NOW    DELAY
    run_layer< 64, 128, 4, 512,  8, 16, true , true , false>(W1, U1, b1, xg, seq, xh, xring, tid);
    __syncthreads();
    run_layer<128,  64, 8, 512,  8,  8, false, false, true >(W2, U2, b2, xg, seq, xh, xring, tid);
    __syncthreads();
    run_layer< 64,  64, 8, 512,  8,  8, false, false, true >(W3, U3, b3, xg, seq, xh, xring, tid);
    __syncthreads();
    run_layer< 64,  32, 8, 256,  8,  8, false, false, false>(W4, U4, b4, xg, seq, xh, xring, tid);
    __syncthreads();

    // ---- FC head: h4 final is in xh[0..32) (L4 perm is identity; T even) ----
    if (tid < 16) {
        float acc = bf[tid];
#pragma unroll
        for (int k = 0; k < 32; ++k) acc = fmaf(xh[k], Wf[k * 16 + tid], acc);
        xh[256 + tid] = fmaxf(acc, 0.0f);
    }
    __syncthreads();
    if (tid == 0) {
        float acc = bo[0];
#pragma unroll
        for (int k = 0; k < 16; ++k) acc = fmaf(xh[256 + k], Wo[k], acc);
        out[blockIdx.x] = acc;
    }
}

extern "C" void kernel_launch(void* const* d_in, const int* in_sizes, int n_in,
                              void* d_out, int out_size, void* d_ws, size_t ws_size,
                              hipStream_t stream) {
    const float* x  = (const float*)d_in[0];
    const float* W1 = (const float*)d_in[1];
    const float* U1 = (const float*)d_in[2];
    const float* b1 = (const float*)d_in[3];
    const float* W2 = (const float*)d_in[4];
    const float* U2 = (const float*)d_in[5];
    const float* b2 = (const float*)d_in[6];
    const float* W3 = (const float*)d_in[7];
    const float* U3 = (const float*)d_in[8];
    const float* b3 = (const float*)d_in[9];
    const float* W4 = (const float*)d_in[10];
    const float* U4 = (const float*)d_in[11];
    const float* b4 = (const float*)d_in[12];
    const float* Wf = (const float*)d_in[13];
    const float* bf = (const float*)d_in[14];
    const float* Wo = (const float*)d_in[15];
    const float* bo = (const float*)d_in[16];
    float* out = (float*)d_out;

    lstm_stack_kernel<<<dim3(256), dim3(NTHREADS), 0, stream>>>(
        x, W1, U1, b1, W2, U2, b2, W3, U3, b3, W4, U4, b4, Wf, bf, Wo, bo, out);
}